// Round 1
// baseline (4895.665 us; speedup 1.0000x reference)
//
#include <hip/hip_runtime.h>
#include <math.h>

#define Hh 8
#define Bb 16
#define Nn 512
#define Dd 512
#define VDd 64
#define FFHh 2048
#define NPICKk 256
#define NORMF 0.125f

// ---------- transpose (H,D,VD) -> (D, H*VD) ----------
__global__ __launch_bounds__(256) void transpose_hw(const float* __restrict__ W,
                                                    float* __restrict__ WT) {
    int i = blockIdx.x * 256 + threadIdx.x;   // over D*H*VD = 262144
    int d = i >> 9;
    int c = i & 511;
    int h = c >> 6;
    int k = c & 63;
    WT[i] = W[h * (Dd * VDd) + d * VDd + k];
}

// ---------- generic fp32 GEMM, 64x64 tile, 256 threads, fused epilogue ----------
// C[r][c] = res + alpha * (relu?(A@B + bias))
// B selected per 64-row tile: rows with (r % 512) < 256 -> B1 else B2 (if do_split)
__global__ __launch_bounds__(256) void gemm_f32(
    const float* __restrict__ A, const float* __restrict__ B1,
    const float* __restrict__ B2, float* __restrict__ C,
    int M, int Nc, int K,
    const float* __restrict__ bias, const float* __restrict__ res,
    const float* __restrict__ alpha, int do_relu, int do_split)
{
    __shared__ __align__(16) float As[16 * 68];   // [k][r], stride 68
    __shared__ __align__(16) float Bs[16 * 64];   // [k][c]
    int tid = threadIdx.x;
    int r0 = blockIdx.y * 64;
    int c0 = blockIdx.x * 64;
    const float* B = (do_split && ((r0 & (Nn - 1)) >= NPICKk)) ? B2 : B1;
    int tx = tid & 15, ty = tid >> 4;
    float acc[4][4] = {};
    int ar = tid >> 2, ak = (tid & 3) * 4;
    int br = tid >> 4, bc = (tid & 15) * 4;
    const float* Aload = A + (size_t)(r0 + ar) * K + ak;
    const float* Bload = B + (size_t)br * Nc + c0 + bc;

    for (int kk = 0; kk < K; kk += 16) {
        float4 a4 = *(const float4*)(Aload + kk);
        float4 b4 = *(const float4*)(Bload + (size_t)kk * Nc);
        __syncthreads();
        As[(ak + 0) * 68 + ar] = a4.x;
        As[(ak + 1) * 68 + ar] = a4.y;
        As[(ak + 2) * 68 + ar] = a4.z;
        As[(ak + 3) * 68 + ar] = a4.w;
        *(float4*)&Bs[br * 64 + bc] = b4;
        __syncthreads();
#pragma unroll
        for (int k = 0; k < 16; ++k) {
            float4 av = *(const float4*)&As[k * 68 + ty * 4];
            float4 bv = *(const float4*)&Bs[k * 64 + tx * 4];
            acc[0][0] += av.x * bv.x; acc[0][1] += av.x * bv.y;
            acc[0][2] += av.x * bv.z; acc[0][3] += av.x * bv.w;
            acc[1][0] += av.y * bv.x; acc[1][1] += av.y * bv.y;
            acc[1][2] += av.y * bv.z; acc[1][3] += av.y * bv.w;
            acc[2][0] += av.z * bv.x; acc[2][1] += av.z * bv.y;
            acc[2][2] += av.z * bv.z; acc[2][3] += av.z * bv.w;
            acc[3][0] += av.w * bv.x; acc[3][1] += av.w * bv.y;
            acc[3][2] += av.w * bv.z; acc[3][3] += av.w * bv.w;
        }
    }

    float alp = alpha ? alpha[0] : 1.0f;
    int c = c0 + tx * 4;
    float4 bv4 = make_float4(0.f, 0.f, 0.f, 0.f);
    if (bias) bv4 = *(const float4*)(bias + c);
#pragma unroll
    for (int i = 0; i < 4; ++i) {
        int r = r0 + ty * 4 + i;
        float4 o;
        o.x = acc[i][0] + bv4.x; o.y = acc[i][1] + bv4.y;
        o.z = acc[i][2] + bv4.z; o.w = acc[i][3] + bv4.w;
        if (do_relu) {
            o.x = fmaxf(o.x, 0.f); o.y = fmaxf(o.y, 0.f);
            o.z = fmaxf(o.z, 0.f); o.w = fmaxf(o.w, 0.f);
        }
        o.x *= alp; o.y *= alp; o.z *= alp; o.w *= alp;
        if (res) {
            float4 r4 = *(const float4*)(res + (size_t)r * Nc + c);
            o.x += r4.x; o.y += r4.y; o.z += r4.z; o.w += r4.w;
        }
        *(float4*)(C + (size_t)r * Nc + c) = o;
    }
}

// ---------- fused attention (online softmax), fp32 ----------
// Layouts: Q/K/V/QA/QB/QD/Out all (B, N, H, VD) flattened.
// HA mode: per column m, score = max-combined {s1 = Q.K[m], sx = QX.K[m]} where
// QX = QA for m<256 else QB; plus a diagonal term QD.K[dix] at column dix.
template <int HA>
__global__ __launch_bounds__(256) void attn_f32(
    const float* __restrict__ Q, const float* __restrict__ Km,
    const float* __restrict__ Vm, const float* __restrict__ QA,
    const float* __restrict__ QB, const float* __restrict__ QD,
    float* __restrict__ Out)
{
    __shared__ __align__(16) float Kt[64 * 68];   // [k][m], stride 68
    __shared__ __align__(16) float Vt[64 * 68];   // [m][v], stride 68
    __shared__ __align__(16) float qrow[4][64];
    __shared__ __align__(16) float qa[4][64];
    __shared__ __align__(16) float qb[4][64];
    __shared__ __align__(16) float qd[4][64];
    __shared__ __align__(16) float pl[4][64];

    int tid = threadIdx.x;
    int w = tid >> 6, lane = tid & 63;
    int b = blockIdx.z, h = blockIdx.y;
    int n = blockIdx.x * 4 + w;
    size_t base = ((size_t)(b * Nn + n) * Hh + h) * VDd;

    qrow[w][lane] = Q[base + lane];
    if (HA) {
        qa[w][lane] = QA[base + lane];
        qb[w][lane] = QB[base + lane];
        qd[w][lane] = QD[base + lane];
    }
    int dix = (n < NPICKk) ? (NPICKk + n) : (n - NPICKk);

    float Mr = -INFINITY, L = 0.f, acc = 0.f;
    int lr = tid >> 2;            // tile row (m) 0..63
    int lc = (tid & 3) * 16;      // col start

    for (int t = 0; t < Nn / 64; ++t) {
        __syncthreads();
        size_t gbase = ((size_t)(b * Nn + t * 64 + lr) * Hh + h) * VDd + lc;
#pragma unroll
        for (int q = 0; q < 4; ++q) {
            float4 k4 = *(const float4*)(Km + gbase + q * 4);
            Kt[(lc + q * 4 + 0) * 68 + lr] = k4.x;
            Kt[(lc + q * 4 + 1) * 68 + lr] = k4.y;
            Kt[(lc + q * 4 + 2) * 68 + lr] = k4.z;
            Kt[(lc + q * 4 + 3) * 68 + lr] = k4.w;
            float4 v4 = *(const float4*)(Vm + gbase + q * 4);
            *(float4*)&Vt[lr * 68 + lc + q * 4] = v4;
        }
        __syncthreads();

        float s1 = 0.f, sx = 0.f;
        const float* qxp = (t * 64 < NPICKk) ? qa[w] : qb[w];
#pragma unroll
        for (int k4 = 0; k4 < 16; ++k4) {
            float4 q4 = *(const float4*)&qrow[w][k4 * 4];
            float kv0 = Kt[(k4 * 4 + 0) * 68 + lane];
            float kv1 = Kt[(k4 * 4 + 1) * 68 + lane];
            float kv2 = Kt[(k4 * 4 + 2) * 68 + lane];
            float kv3 = Kt[(k4 * 4 + 3) * 68 + lane];
            s1 += q4.x * kv0 + q4.y * kv1 + q4.z * kv2 + q4.w * kv3;
            if (HA) {
                float4 x4 = *(const float4*)&qxp[k4 * 4];
                sx += x4.x * kv0 + x4.y * kv1 + x4.z * kv2 + x4.w * kv3;
            }
        }
        s1 *= NORMF; sx *= NORMF;

        bool isd = HA && (t * 64 + lane == dix);
        float sd = -INFINITY;
        if (isd) {
            float sdd = 0.f;
            for (int k = 0; k < 64; ++k) sdd += qd[w][k] * Kt[k * 68 + lane];
            sd = sdd * NORMF;
        }

        float tm = s1;
        if (HA) tm = fmaxf(tm, sx);
        if (isd) tm = fmaxf(tm, sd);
#pragma unroll
        for (int o = 32; o >= 1; o >>= 1) tm = fmaxf(tm, __shfl_xor(tm, o));

        float Mn = fmaxf(Mr, tm);
        float scl = __expf(Mr - Mn);
        acc *= scl; L *= scl; Mr = Mn;

        float e = __expf(s1 - Mr);
        if (HA) e += __expf(sx - Mr);
        if (isd) e += __expf(sd - Mr);
        pl[w][lane] = e;
        float es = e;
#pragma unroll
        for (int o = 32; o >= 1; o >>= 1) es += __shfl_xor(es, o);
        L += es;
        __syncthreads();

#pragma unroll
        for (int m4 = 0; m4 < 16; ++m4) {
            float4 p4 = *(const float4*)&pl[w][m4 * 4];
            acc += p4.x * Vt[(m4 * 4 + 0) * 68 + lane]
                 + p4.y * Vt[(m4 * 4 + 1) * 68 + lane]
                 + p4.z * Vt[(m4 * 4 + 2) * 68 + lane]
                 + p4.w * Vt[(m4 * 4 + 3) * 68 + lane];
        }
    }
    Out[base + lane] = acc / L;
}

extern "C" void kernel_launch(void* const* d_in, const int* in_sizes, int n_in,
                              void* d_out, int out_size, void* d_ws, size_t ws_size,
                              hipStream_t stream)
{
    const float* x = (const float*)d_in[0];

    // Resolve input ordering: setup_inputs dict order vs reference arg order.
    // dict: 17=comb_w 18=comb2_w 19=comb3_w 20=comb_b 21=comb2_b 22=comb3_b
    // args: 17=comb_w 18=comb_b 19=comb2_w 20=comb2_b 21=comb3_w 22=comb3_b
    int dictOrder = (in_sizes[18] != 512);
    const float* comb_w  = (const float*)d_in[17];
    const float* comb2_w = (const float*)d_in[dictOrder ? 18 : 19];
    const float* comb3_w = (const float*)d_in[dictOrder ? 19 : 21];
    const float* comb_b  = (const float*)d_in[dictOrder ? 20 : 18];
    const float* comb2_b = (const float*)d_in[dictOrder ? 21 : 20];
    const float* comb3_b = (const float*)d_in[22];
    const float* alpha1 = (const float*)d_in[23];
    const float* alpha2 = (const float*)d_in[24];
    const float* alpha3 = (const float*)d_in[25];
    const float* ff1_w1 = (const float*)d_in[26];
    const float* ff1_b1 = (const float*)d_in[27];
    const float* ff1_w2 = (const float*)d_in[28];
    const float* ff1_b2 = (const float*)d_in[29];
    const float* ffa1   = (const float*)d_in[30];
    const float* ff2_w1 = (const float*)d_in[31];
    const float* ff2_b1 = (const float*)d_in[32];
    const float* ff2_w2 = (const float*)d_in[33];
    const float* ff2_b2 = (const float*)d_in[34];
    const float* ffa2   = (const float*)d_in[35];
    const float* ff3_w1 = (const float*)d_in[36];
    const float* ff3_b1 = (const float*)d_in[37];
    const float* ff3_w2 = (const float*)d_in[38];
    const float* ff3_b2 = (const float*)d_in[39];
    const float* ffa3   = (const float*)d_in[40];
    const float* Wq_w   = (const float*)d_in[10];
    const float* Wk_w   = (const float*)d_in[11];
    const float* Wv_w   = (const float*)d_in[12];
    const float* Wq2p_w = (const float*)d_in[13];
    const float* Wq2d_w = (const float*)d_in[14];
    const float* Wk2_w  = (const float*)d_in[15];
    const float* Wv2_w  = (const float*)d_in[16];

    // Workspace layout (floats)
    float* WT = (float*)d_ws;
    const size_t WSZ = 512 * 512;            // per transposed weight
    const size_t SB = (size_t)Bb * Nn * 512; // 4,194,304
    float* bufQ  = WT + 9 * WSZ;
    float* bufK  = bufQ + SB;
    float* bufV  = bufK + SB;
    float* bufQA = bufV + SB;
    float* bufQB = bufQA + SB;
    float* bufQD = bufQB + SB;
    float* bufHA = bufQD + SB;
    float* tmp   = bufQ;        // FF hidden (B*N*2048) aliases bufQ..bufQA (dead then)
    float* cur   = (float*)d_out;

    dim3 tb(256);

    // 1. transpose the 9 per-head weights: WT0..WT8 = Wq,Wk,Wv,W1..W6
    for (int i = 0; i < 9; ++i)
        hipLaunchKernelGGL(transpose_hw, dim3(1024), tb, 0, stream,
                           (const float*)d_in[1 + i], WT + i * WSZ);

    auto gemm = [&](const float* A, const float* B1v, const float* B2v, float* Cv,
                    int M, int Ncc, int Kc, const float* bias, const float* res,
                    const float* alp, int relu, int split) {
        hipLaunchKernelGGL(gemm_f32, dim3(Ncc / 64, M / 64), tb, 0, stream,
                           A, B1v, B2v, Cv, M, Ncc, Kc, bias, res, alp, relu, split);
    };
    const int TOK = Bb * Nn;  // 8192

    // 2. HA projections
    gemm(x, WT + 0 * WSZ, WT + 0 * WSZ, bufQ,  TOK, 512, 512, nullptr, nullptr, nullptr, 0, 0);
    gemm(x, WT + 1 * WSZ, WT + 1 * WSZ, bufK,  TOK, 512, 512, nullptr, nullptr, nullptr, 0, 0);
    gemm(x, WT + 2 * WSZ, WT + 2 * WSZ, bufV,  TOK, 512, 512, nullptr, nullptr, nullptr, 0, 0);
    gemm(x, WT + 4 * WSZ, WT + 8 * WSZ, bufQA, TOK, 512, 512, nullptr, nullptr, nullptr, 0, 1); // W2/W6
    gemm(x, WT + 5 * WSZ, WT + 7 * WSZ, bufQB, TOK, 512, 512, nullptr, nullptr, nullptr, 0, 1); // W3/W5
    gemm(x, WT + 3 * WSZ, WT + 6 * WSZ, bufQD, TOK, 512, 512, nullptr, nullptr, nullptr, 0, 1); // W1/W4

    // 3. HA fused attention -> bufHA
    hipLaunchKernelGGL((attn_f32<1>), dim3(Nn / 4, Hh, Bb), tb, 0, stream,
                       bufQ, bufK, bufV, bufQA, bufQB, bufQD, bufHA);

    // 4. cur = x + alpha3*(ha @ comb3_w + comb3_b)
    gemm(bufHA, comb3_w, comb3_w, cur, TOK, 512, 512, comb3_b, x, alpha3, 0, 0);

    // 5. FF3
    gemm(cur, ff3_w1, ff3_w1, tmp, TOK, 2048, 512, ff3_b1, nullptr, nullptr, 1, 0);
    gemm(tmp, ff3_w2, ff3_w2, cur, TOK, 512, 2048, ff3_b2, cur, ffa3, 0, 0);

    // 6. MHA1
    gemm(cur, Wq_w, Wq_w, bufQ, TOK, 512, 512, nullptr, nullptr, nullptr, 0, 0);
    gemm(cur, Wk_w, Wk_w, bufK, TOK, 512, 512, nullptr, nullptr, nullptr, 0, 0);
    gemm(cur, Wv_w, Wv_w, bufV, TOK, 512, 512, nullptr, nullptr, nullptr, 0, 0);
    hipLaunchKernelGGL((attn_f32<0>), dim3(Nn / 4, Hh, Bb), tb, 0, stream,
                       bufQ, bufK, bufV, bufQ, bufQ, bufQ, bufHA);
    gemm(bufHA, comb_w, comb_w, cur, TOK, 512, 512, comb_b, cur, alpha1, 0, 0);

    // 7. FF1
    gemm(cur, ff1_w1, ff1_w1, tmp, TOK, 2048, 512, ff1_b1, nullptr, nullptr, 1, 0);
    gemm(tmp, ff1_w2, ff1_w2, cur, TOK, 512, 2048, ff1_b2, cur, ffa1, 0, 0);

    // 8. MHA2 (q2 uses Wq2p for pick rows, Wq2d for dlv rows)
    gemm(cur, Wq2p_w, Wq2d_w, bufQ, TOK, 512, 512, nullptr, nullptr, nullptr, 0, 1);
    gemm(cur, Wk2_w, Wk2_w, bufK, TOK, 512, 512, nullptr, nullptr, nullptr, 0, 0);
    gemm(cur, Wv2_w, Wv2_w, bufV, TOK, 512, 512, nullptr, nullptr, nullptr, 0, 0);
    hipLaunchKernelGGL((attn_f32<0>), dim3(Nn / 4, Hh, Bb), tb, 0, stream,
                       bufQ, bufK, bufV, bufQ, bufQ, bufQ, bufHA);
    gemm(bufHA, comb2_w, comb2_w, cur, TOK, 512, 512, comb2_b, cur, alpha2, 0, 0);

    // 9. FF2 -> final output in cur == d_out
    gemm(cur, ff2_w1, ff2_w1, tmp, TOK, 2048, 512, ff2_b1, nullptr, nullptr, 1, 0);
    gemm(tmp, ff2_w2, ff2_w2, cur, TOK, 512, 2048, ff2_b2, cur, ffa2, 0, 0);
}